// Round 1
// baseline (9191.693 us; speedup 1.0000x reference)
//
#include <hip/hip_runtime.h>
#include <hip/hip_bf16.h>
#include <math.h>

// GPT-2 small forward: B=2, S=1024, V=50257, E=768, H=12, L=4, D=64
// All fp32 this round (correctness baseline).

#define Bb 2
#define Ss 1024
#define Vv 50257
#define Ee 768
#define Hh 12
#define Ll 4
#define Dd 64
#define E3 2304   // 3*E
#define E4 3072   // 4*E
#define ROWS 2048 // B*S

// ---------------------------------------------------------------------------
// Embedding: x[row] = wte[ids[row]] + wpe[row % S]
// ---------------------------------------------------------------------------
__global__ __launch_bounds__(256) void embed_kernel(
    const int* __restrict__ ids, const float* __restrict__ wte,
    const float* __restrict__ wpe, float* __restrict__ x)
{
    int row = blockIdx.x;
    int s = row & (Ss - 1);
    int id = ids[row];
    const float* wt = wte + (size_t)id * Ee;
    const float* wp = wpe + (size_t)s * Ee;
    float* xr = x + (size_t)row * Ee;
    for (int i = 0; i < 3; ++i) {
        int c = threadIdx.x + i * 256;
        xr[c] = wt[c] + wp[c];
    }
}

// ---------------------------------------------------------------------------
// LayerNorm: one block (256 thr) per row of 768
// ---------------------------------------------------------------------------
__global__ __launch_bounds__(256) void ln_kernel(
    const float* __restrict__ x, const float* __restrict__ gain,
    const float* __restrict__ bias, float* __restrict__ out)
{
    int row = blockIdx.x;
    int tid = threadIdx.x;
    const float* xr = x + (size_t)row * Ee;
    float v0 = xr[tid], v1 = xr[tid + 256], v2 = xr[tid + 512];

    __shared__ float red1[4];
    __shared__ float red2[4];

    float sum = v0 + v1 + v2;
    #pragma unroll
    for (int o = 32; o > 0; o >>= 1) sum += __shfl_down(sum, o, 64);
    if ((tid & 63) == 0) red1[tid >> 6] = sum;
    __syncthreads();
    float mu = (red1[0] + red1[1] + red1[2] + red1[3]) * (1.0f / 768.0f);

    float d0 = v0 - mu, d1 = v1 - mu, d2 = v2 - mu;
    float vs = d0 * d0 + d1 * d1 + d2 * d2;
    #pragma unroll
    for (int o = 32; o > 0; o >>= 1) vs += __shfl_down(vs, o, 64);
    if ((tid & 63) == 0) red2[tid >> 6] = vs;
    __syncthreads();
    float var = (red2[0] + red2[1] + red2[2] + red2[3]) * (1.0f / 768.0f);
    float rs = rsqrtf(var + 1e-6f);

    float* orow = out + (size_t)row * Ee;
    orow[tid]       = d0 * rs * gain[tid]       + bias[tid];
    orow[tid + 256] = d1 * rs * gain[tid + 256] + bias[tid + 256];
    orow[tid + 512] = d2 * rs * gain[tid + 512] + bias[tid + 512];
}

// ---------------------------------------------------------------------------
// Tiled fp32 GEMM: C[M,N] = act(A[M,K] @ W[K,N] + bias) (+ R)
// 64x64 tile, BK=16, 256 threads, 4x4 micro-tile/thread.
// ACT: 0 none, 1 gelu(tanh approx). RES: add R elementwise.
// ---------------------------------------------------------------------------
__device__ __forceinline__ float gelu_f(float x) {
    const float k = 0.7978845608028654f; // sqrt(2/pi)
    float x3 = x * x * x;
    return 0.5f * x * (1.0f + tanhf(k * (x + 0.044715f * x3)));
}

template <int ACT, int RES>
__global__ __launch_bounds__(256) void gemm_kernel(
    const float* __restrict__ A, const float* __restrict__ W,
    const float* __restrict__ bias, const float* __restrict__ R,
    float* __restrict__ C, int M, int N, int K)
{
    __shared__ float As[16][64]; // [k][m]
    __shared__ float Ws[16][64]; // [k][n]

    int tid = threadIdx.x;
    int m0 = blockIdx.y * 64;
    int n0 = blockIdx.x * 64;
    int tx = tid & 15, ty = tid >> 4;

    float acc[4][4] = {};

    for (int kb = 0; kb < K; kb += 16) {
        // A tile: 64 rows x 16 k. K is always a multiple of 16 here.
        #pragma unroll
        for (int i = 0; i < 4; ++i) {
            int idx = tid + i * 256;
            int r = idx >> 4, kk = idx & 15;
            int gm = m0 + r;
            As[kk][r] = (gm < M) ? A[(size_t)gm * K + (kb + kk)] : 0.0f;
        }
        // W tile: 16 k x 64 n
        #pragma unroll
        for (int i = 0; i < 4; ++i) {
            int idx = tid + i * 256;
            int kk = idx >> 6, n = idx & 63;
            int gn = n0 + n;
            Ws[kk][n] = (gn < N) ? W[(size_t)(kb + kk) * N + gn] : 0.0f;
        }
        __syncthreads();
        #pragma unroll
        for (int kk = 0; kk < 16; ++kk) {
            const float4 a4 = *reinterpret_cast<const float4*>(&As[kk][ty * 4]);
            const float4 w4 = *reinterpret_cast<const float4*>(&Ws[kk][tx * 4]);
            float av[4] = {a4.x, a4.y, a4.z, a4.w};
            float wv[4] = {w4.x, w4.y, w4.z, w4.w};
            #pragma unroll
            for (int i = 0; i < 4; ++i)
                #pragma unroll
                for (int j = 0; j < 4; ++j)
                    acc[i][j] = fmaf(av[i], wv[j], acc[i][j]);
        }
        __syncthreads();
    }

    #pragma unroll
    for (int i = 0; i < 4; ++i) {
        int gm = m0 + ty * 4 + i;
        if (gm >= M) continue;
        #pragma unroll
        for (int j = 0; j < 4; ++j) {
            int gn = n0 + tx * 4 + j;
            if (gn >= N) continue;
            float v = acc[i][j];
            if (bias) v += bias[gn];
            if (ACT == 1) v = gelu_f(v);
            if (RES) v += R[(size_t)gm * N + gn];
            C[(size_t)gm * N + gn] = v;
        }
    }
}

// ---------------------------------------------------------------------------
// Flash-style causal attention, fp32, 64x64 tiles.
// grid (qtile=16, head=12, batch=2), block 256.
// qkv: [2048][2304]; q at col h*64, k at 768+h*64, v at 1536+h*64.
// out: [2048][768]
// ---------------------------------------------------------------------------
__global__ __launch_bounds__(256) void attn_kernel(
    const float* __restrict__ qkv, float* __restrict__ out)
{
    int qt = blockIdx.x, h = blockIdx.y, b = blockIdx.z;
    __shared__ float Qs[64][65];
    __shared__ float Ks[64][65];
    __shared__ float Vs[64][65];
    __shared__ float Ps[64][65];

    int tid = threadIdx.x;
    int base_row = b * Ss;
    int colq = h * Dd;

    // load Q tile
    for (int i = 0; i < 16; ++i) {
        int idx = tid + i * 256;
        int r = idx >> 6, d = idx & 63;
        Qs[r][d] = qkv[(size_t)(base_row + qt * 64 + r) * E3 + colq + d];
    }

    int r = tid >> 2;            // my row within tile (0..63)
    int dq = (tid & 3) * 16;     // my dim slice start
    int qrow_g = qt * 64 + r;    // global q index within sequence

    float O[16];
    #pragma unroll
    for (int i = 0; i < 16; ++i) O[i] = 0.0f;
    float mrow = -1e30f, lrow = 0.0f;

    for (int kt = 0; kt <= qt; ++kt) {
        __syncthreads();
        for (int i = 0; i < 16; ++i) {
            int idx = tid + i * 256;
            int rr = idx >> 6, d = idx & 63;
            size_t off = (size_t)(base_row + kt * 64 + rr) * E3 + colq;
            Ks[rr][d] = qkv[off + 768 + d];
            Vs[rr][d] = qkv[off + 1536 + d];
        }
        __syncthreads();

        // scores for my row r, cols dq..dq+15
        for (int j = 0; j < 16; ++j) {
            int kc = dq + j;
            float sacc = 0.0f;
            #pragma unroll 8
            for (int d = 0; d < 64; ++d) sacc = fmaf(Qs[r][d], Ks[kc][d], sacc);
            sacc *= 0.125f; // 1/sqrt(64)
            if (kt == qt && (kt * 64 + kc) > qrow_g) sacc = -10000.0f;
            Ps[r][kc] = sacc;
        }
        __syncthreads();

        // online softmax update for row r
        float tmax = -1e30f;
        for (int j = 0; j < 64; ++j) tmax = fmaxf(tmax, Ps[r][j]);
        float mnew = fmaxf(mrow, tmax);
        float alpha = __expf(mrow - mnew);
        #pragma unroll
        for (int i = 0; i < 16; ++i) O[i] *= alpha;
        float psum = 0.0f;
        for (int j = 0; j < 64; ++j) {
            float p = __expf(Ps[r][j] - mnew);
            psum += p;
            #pragma unroll
            for (int i = 0; i < 16; ++i) O[i] = fmaf(p, Vs[j][dq + i], O[i]);
        }
        lrow = lrow * alpha + psum;
        mrow = mnew;
    }

    float inv = 1.0f / lrow;
    float* orow = out + (size_t)(base_row + qt * 64 + r) * Ee + colq + dq;
    #pragma unroll
    for (int i = 0; i < 16; ++i) orow[i] = O[i] * inv;
}

// ---------------------------------------------------------------------------
// Host orchestration
// ---------------------------------------------------------------------------
extern "C" void kernel_launch(void* const* d_in, const int* in_sizes, int n_in,
                              void* d_out, int out_size, void* d_ws, size_t ws_size,
                              hipStream_t stream)
{
    const int*   ids   = (const int*)  d_in[0];
    const float* wte   = (const float*)d_in[1];
    const float* wpe   = (const float*)d_in[2];
    const float* ln1_s = (const float*)d_in[3];
    const float* ln1_b = (const float*)d_in[4];
    const float* w_qkv = (const float*)d_in[5];
    const float* b_qkv = (const float*)d_in[6];
    const float* w_ao  = (const float*)d_in[7];
    const float* b_ao  = (const float*)d_in[8];
    const float* ln2_s = (const float*)d_in[9];
    const float* ln2_b = (const float*)d_in[10];
    const float* w_fc  = (const float*)d_in[11];
    const float* b_fc  = (const float*)d_in[12];
    const float* w_mp  = (const float*)d_in[13];
    const float* b_mp  = (const float*)d_in[14];
    const float* lnf_s = (const float*)d_in[15];
    const float* lnf_b = (const float*)d_in[16];
    const float* w_lm  = (const float*)d_in[17];
    float* out = (float*)d_out;

    // workspace layout (floats): x, h, qkv, attno, hfc  -> 15.73M floats (62.9 MB)
    float* ws    = (float*)d_ws;
    float* x     = ws;
    float* hbuf  = x     + (size_t)ROWS * Ee;
    float* qkvb  = hbuf  + (size_t)ROWS * Ee;
    float* attno = qkvb  + (size_t)ROWS * E3;
    float* hfc   = attno + (size_t)ROWS * Ee;

    embed_kernel<<<ROWS, 256, 0, stream>>>(ids, wte, wpe, x);

    for (int l = 0; l < Ll; ++l) {
        // LN1
        ln_kernel<<<ROWS, 256, 0, stream>>>(x, ln1_s + l * Ee, ln1_b + l * Ee, hbuf);
        // qkv = h @ w_qkv + b_qkv   [2048, 2304]
        gemm_kernel<0, 0><<<dim3(E3 / 64, ROWS / 64), 256, 0, stream>>>(
            hbuf, w_qkv + (size_t)l * Ee * E3, b_qkv + (size_t)l * E3, nullptr,
            qkvb, ROWS, E3, Ee);
        // attention
        attn_kernel<<<dim3(16, Hh, Bb), 256, 0, stream>>>(qkvb, attno);
        // x = x + attno @ w_ao + b_ao
        gemm_kernel<0, 1><<<dim3(Ee / 64, ROWS / 64), 256, 0, stream>>>(
            attno, w_ao + (size_t)l * Ee * Ee, b_ao + (size_t)l * Ee, x,
            x, ROWS, Ee, Ee);
        // LN2
        ln_kernel<<<ROWS, 256, 0, stream>>>(x, ln2_s + l * Ee, ln2_b + l * Ee, hbuf);
        // hfc = gelu(h @ w_fc + b_fc)   [2048, 3072]
        gemm_kernel<1, 0><<<dim3(E4 / 64, ROWS / 64), 256, 0, stream>>>(
            hbuf, w_fc + (size_t)l * Ee * E4, b_fc + (size_t)l * E4, nullptr,
            hfc, ROWS, E4, Ee);
        // x = x + hfc @ w_mp + b_mp
        gemm_kernel<0, 1><<<dim3(Ee / 64, ROWS / 64), 256, 0, stream>>>(
            hfc, w_mp + (size_t)l * E4 * Ee, b_mp + (size_t)l * Ee, x,
            x, ROWS, Ee, E4);
    }

    // final LN
    ln_kernel<<<ROWS, 256, 0, stream>>>(x, lnf_s, lnf_b, hbuf);
    // logits = h @ w_lm   [2048, 50257]
    gemm_kernel<0, 0><<<dim3((Vv + 63) / 64, ROWS / 64), 256, 0, stream>>>(
        hbuf, w_lm, nullptr, nullptr, out, ROWS, Vv, Ee);
}